// Round 10
// baseline (138.706 us; speedup 1.0000x reference)
//
#include <hip/hip_runtime.h>
#include <hip/hip_bf16.h>
#include <math.h>

// B=4, NB=2048 -> 8192 leaf blocks of L=16 tokens x C=128; H=8 heads x D=16.
// 512 threads (8 waves), NITER=4 blocks/WG, TWO barriers per iteration.
// Wave w owns q/k/v col-tile w, its OWN gate column (shuffle), head w, proj cols
// [w*16,w*16+16). Waves 0-3 run the edge MLP. v_blk lives in registers.
typedef __attribute__((ext_vector_type(8))) short bf16x8;
typedef __attribute__((ext_vector_type(4))) float f32x4;
typedef __attribute__((ext_vector_type(4))) unsigned short us4;
typedef __attribute__((ext_vector_type(2))) unsigned int u32x2;

#define NITER 4

struct bfpair { unsigned short hi, lo; };

static __device__ __forceinline__ unsigned short f2bf_rn(float f) {
    union { __hip_bfloat16 h; unsigned short u; } cv;
    cv.h = __float2bfloat16(f);
    return cv.u;
}
static __device__ __forceinline__ float bf2f(unsigned short u) {
    union { unsigned int i; float f; } cv;
    cv.i = ((unsigned int)u) << 16;
    return cv.f;
}
static __device__ __forceinline__ bfpair split2(float f) {
    bfpair p;
    unsigned int u = __float_as_uint(f);
    p.hi = (unsigned short)(u >> 16);
    float r = f - __uint_as_float(u & 0xffff0000u);
    p.lo = (unsigned short)(__float_as_uint(r) >> 16);
    return p;
}
static __device__ __forceinline__ f32x4 MFMA(bf16x8 a, bf16x8 b, f32x4 c) {
    return __builtin_amdgcn_mfma_f32_16x16x32_bf16(a, b, c, 0, 0, 0);
}
static __device__ __forceinline__ float sigmoid_fast(float t) {
    return __builtin_amdgcn_rcpf(1.f + __expf(-t));
}

// ---- prep: Wbig = bf16([Wqkv(384); Wbr(8); zeros(8)]) [400][128]; Wp = bf16(Wproj)
__global__ __launch_bounds__(256) void prep_kernel(
    const float* __restrict__ Wqkv, const float* __restrict__ Wbr,
    const float* __restrict__ Wproj,
    unsigned short* __restrict__ Wbig, unsigned short* __restrict__ Wp)
{
    int i = blockIdx.x * 256 + threadIdx.x;
    if (i < 400 * 128) {
        int n = i >> 7, k = i & 127;
        float v = (n < 384) ? Wqkv[i] : (n < 392 ? Wbr[(n - 384) * 128 + k] : 0.f);
        Wbig[i] = f2bf_rn(v);
    } else {
        int j = i - 400 * 128;
        if (j < 128 * 128) Wp[j] = f2bf_rn(Wproj[j]);
    }
}

__global__ __launch_bounds__(512) void leaf_main(
    const float* __restrict__ x, const int* __restrict__ mask,
    const float* __restrict__ edge,
    const unsigned short* __restrict__ Wbig, const unsigned short* __restrict__ Wp,
    const float* __restrict__ bqkv, const float* __restrict__ bproj,
    const float* __restrict__ eg_w1, const float* __restrict__ eg_b1,
    const float* __restrict__ eg_w2, const float* __restrict__ eg_b2,
    const float* __restrict__ bbr, float* __restrict__ out)
{
    __shared__ unsigned short qhiS[16 * 136], qloS[16 * 136];  // q hi/lo
    __shared__ unsigned short khiS[16 * 136];                  // k rounded
    __shared__ unsigned short vtS[128 * 24];                   // [h*16+d][tok(24)]
    __shared__ unsigned short ewS[8 * 256];                    // [h][q*16+k]
    __shared__ float logitS[256];                              // [q*16+k]
    __shared__ unsigned short pS[8 * 16 * 24];                 // per-wave P
    __shared__ unsigned short mhiS[16 * 136];                  // x_mid rounded
    __shared__ unsigned short xhiS[16 * 128], xloS[16 * 128];  // x stage (dedicated)
    // total ~39 KB

    const int tid  = threadIdx.x;
    const int lane = tid & 63;
    const int wave = tid >> 6;
    const int c15  = lane & 15;
    const int quad = lane >> 4;
    const bf16x8 zf = {0, 0, 0, 0, 0, 0, 0, 0};
    const int bid0 = blockIdx.x * NITER;

    // iteration-invariant
    const unsigned short* wbase = Wbig + c15 * 128 + quad * 8;
    const float bq0 = bqkv[wave * 16 + c15];
    const float bq1 = bqkv[128 + wave * 16 + c15];
    const float bq2 = bqkv[256 + wave * 16 + c15];
    const float bgate = bbr[c15 & 7];          // bias for gate col c15 (c15<8 valid)
    const float bpv = bproj[wave * 16 + c15];

    // ---- prologue: block 0 inputs ----
    int mv = 0;
    float4 evv = make_float4(0.f, 0.f, 0.f, 0.f);
    if (tid < 256) {
        mv  = mask[(size_t)bid0 * 256 + tid];
        evv = *(const float4*)&edge[((size_t)bid0 * 256 + tid) * 4];
    }
    float4 xv = ((const float4*)(x + (size_t)bid0 * 2048))[tid];

    // W rolling prefetch: slot0 = q-tile(wave), slot1 = k-tile(8+wave)
    bf16x8 Bt[2][4];
    {
        const unsigned short* w0 = wbase + (wave * 16) * 128;
        #pragma unroll
        for (int kk = 0; kk < 4; ++kk) Bt[0][kk] = *(const bf16x8*)(w0 + kk * 32);
        const unsigned short* w1 = wbase + ((8 + wave) * 16) * 128;
        #pragma unroll
        for (int kk = 0; kk < 4; ++kk) Bt[1][kk] = *(const bf16x8*)(w1 + kk * 32);
    }

    // stage x block 0 (trunc split, chunk-XOR swizzle)
    {
        int row = tid >> 5, c4 = tid & 31;
        int off = row * 128 + (((c4 >> 1) ^ (row & 7)) << 3) + ((c4 & 1) << 2);
        float f[4] = {xv.x, xv.y, xv.z, xv.w};
        us4 hi, lo;
        #pragma unroll
        for (int j = 0; j < 4; ++j) {
            bfpair p = split2(f[j]);
            hi[j] = p.hi;
            lo[j] = p.lo;
        }
        *(us4*)&xhiS[off] = hi;
        *(us4*)&xloS[off] = lo;
    }
    __syncthreads();   // prologue barrier: x0 staged

    #pragma unroll 1
    for (int it = 0; it < NITER; ++it) {
        const int bid = bid0 + it;
        const bool more = (it + 1 < NITER);

        // next-block loads (retire under this iteration's compute)
        float4 xv_n = make_float4(0.f, 0.f, 0.f, 0.f);
        int mv_n = 0;
        float4 ev_n = make_float4(0.f, 0.f, 0.f, 0.f);
        if (more) {
            xv_n = ((const float4*)(x + (size_t)(bid + 1) * 2048))[tid];
            if (tid < 256) {
                mv_n = mask[(size_t)(bid + 1) * 256 + tid];
                ev_n = *(const float4*)&edge[((size_t)(bid + 1) * 256 + tid) * 4];
            }
        }

        // ---- edge-gate MLP (poly gelu) + mask/logits (waves 0-3) ----
        if (tid < 256) {
            const int q = tid >> 4, k = tid & 15;
            int s = mv;
            s += __shfl_xor(s, 1); s += __shfl_xor(s, 2);
            s += __shfl_xor(s, 4); s += __shfl_xor(s, 8);
            float m = (float)mv;
            if (q == k && s < 1) m = 1.f;
            float bp0, bp1, bp2, bp3;
            if (q == k) { bp0 = bp1 = bp2 = 0.f; bp3 = 1.f; }
            else        { bp0 = evv.x; bp1 = evv.y; bp2 = evv.z; bp3 = evv.w; }
            logitS[tid] = (m == 0.f) ? -INFINITY : bp3;
            float ew[8];
            #pragma unroll
            for (int h = 0; h < 8; ++h) ew[h] = eg_b2[h];
            #pragma unroll
            for (int j = 0; j < 16; ++j) {
                float z = eg_w1[j * 4 + 0] * bp0 + eg_w1[j * 4 + 1] * bp1 +
                          eg_w1[j * 4 + 2] * bp2 + eg_w1[j * 4 + 3] * bp3 + eg_b1[j];
                float u = z * z;
                float w = __builtin_fmaf(-0.0664904f, u, 0.3989423f);
                float g = z * __builtin_fmaf(z, w, 0.5f);
                #pragma unroll
                for (int h = 0; h < 8; ++h) ew[h] = __builtin_fmaf(eg_w2[h * 16 + j], g, ew[h]);
            }
            #pragma unroll
            for (int h = 0; h < 8; ++h)
                ewS[h * 256 + tid] = (m == 0.f) ? (unsigned short)0
                                   : (unsigned short)(__float_as_uint(ew[h]) >> 16);
        }

        // ---- A-fragments from LDS ----
        bf16x8 ah[4], al[4];
        #pragma unroll
        for (int kk = 0; kk < 4; ++kk) {
            int off = c15 * 128 + (((kk * 4 + quad) ^ (c15 & 7)) << 3);
            ah[kk] = *(const bf16x8*)&xhiS[off];
            al[kk] = *(const bf16x8*)&xloS[off];
        }

        const int colq = wave * 16 + c15;
        float vblk;
        float greg[4];

        // ---- tile q (hi/lo split) ----
        {
            f32x4 acc = {0.f, 0.f, 0.f, 0.f};
            #pragma unroll
            for (int kk = 0; kk < 4; ++kk) {
                acc = MFMA(ah[kk], Bt[0][kk], acc);
                acc = MFMA(al[kk], Bt[0][kk], acc);
            }
            const unsigned short* w2 = wbase + ((16 + wave) * 16) * 128;  // v-tile
            #pragma unroll
            for (int kk = 0; kk < 4; ++kk) Bt[0][kk] = *(const bf16x8*)(w2 + kk * 32);
            #pragma unroll
            for (int r = 0; r < 4; ++r) {
                bfpair p = split2(acc[r] + bq0);
                qhiS[(quad * 4 + r) * 136 + colq] = p.hi;
                qloS[(quad * 4 + r) * 136 + colq] = p.lo;
            }
        }

        // ---- tile k (rounded) ----
        {
            f32x4 acc = {0.f, 0.f, 0.f, 0.f};
            #pragma unroll
            for (int kk = 0; kk < 4; ++kk) {
                acc = MFMA(ah[kk], Bt[1][kk], acc);
                acc = MFMA(al[kk], Bt[1][kk], acc);
            }
            const unsigned short* w3 = wbase + 384 * 128;                 // gate tile
            #pragma unroll
            for (int kk = 0; kk < 4; ++kk) Bt[1][kk] = *(const bf16x8*)(w3 + kk * 32);
            #pragma unroll
            for (int r = 0; r < 4; ++r)
                khiS[(quad * 4 + r) * 136 + colq] = f2bf_rn(acc[r] + bq1);
        }

        // ---- tile v (transposed; v_blk in-register) ----
        {
            f32x4 acc = {0.f, 0.f, 0.f, 0.f};
            #pragma unroll
            for (int kk = 0; kk < 4; ++kk) {
                acc = MFMA(ah[kk], Bt[0][kk], acc);
                acc = MFMA(al[kk], Bt[0][kk], acc);
            }
            const unsigned short* w0 = wbase + (wave * 16) * 128;         // next q
            #pragma unroll
            for (int kk = 0; kk < 4; ++kk) Bt[0][kk] = *(const bf16x8*)(w0 + kk * 32);
            us4 vw;
            #pragma unroll
            for (int r = 0; r < 4; ++r) vw[r] = f2bf_rn(acc[r] + bq2);
            *(us4*)&vtS[colq * 24 + quad * 4] = vw;
            float s = acc[0] + acc[1] + acc[2] + acc[3];
            s += __shfl_xor(s, 16);
            s += __shfl_xor(s, 32);
            vblk = s * 0.0625f + bq2;     // per-lane = v_blk[wave*16+c15]
        }

        // ---- tile gate (every wave; keep own column via shuffle) ----
        {
            f32x4 acc = {0.f, 0.f, 0.f, 0.f};
            #pragma unroll
            for (int kk = 0; kk < 4; ++kk) {
                acc = MFMA(ah[kk], Bt[1][kk], acc);
                acc = MFMA(al[kk], Bt[1][kk], acc);
            }
            const unsigned short* w1 = wbase + ((8 + wave) * 16) * 128;   // next k
            #pragma unroll
            for (int kk = 0; kk < 4; ++kk) Bt[1][kk] = *(const bf16x8*)(w1 + kk * 32);
            const int src = (lane & 48) | wave;   // lane holding col = wave, same quad
            #pragma unroll
            for (int r = 0; r < 4; ++r) {
                float sg = sigmoid_fast(acc[r] + bgate);
                greg[r] = __shfl(sg, src);        // g[tok=quad*4+r][h=wave]
            }
        }
        __syncthreads();   // barrier B: qkv/MLP visible; x-stage reads done

        // stage NEXT block's x (overlaps attention; visibility covered by barrier C)
        if (more) {
            int row = tid >> 5, c4 = tid & 31;
            int off = row * 128 + (((c4 >> 1) ^ (row & 7)) << 3) + ((c4 & 1) << 2);
            float f[4] = {xv_n.x, xv_n.y, xv_n.z, xv_n.w};
            us4 hi, lo;
            #pragma unroll
            for (int j = 0; j < 4; ++j) {
                bfpair p = split2(f[j]);
                hi[j] = p.hi;
                lo[j] = p.lo;
            }
            *(us4*)&xhiS[off] = hi;
            *(us4*)&xloS[off] = lo;
        }

        // proj weights prefetch (retire under attention)
        bf16x8 Wt[4];
        {
            const unsigned short* wp = Wp + (wave * 16 + c15) * 128 + quad * 8;
            #pragma unroll
            for (int kk = 0; kk < 4; ++kk) Wt[kk] = *(const bf16x8*)(wp + kk * 32);
        }

        // ---- attention, swapped QK^T (head h = wave) ----
        {
            const int h = wave;
            const int fo = c15 * 136 + h * 16 + (quad & 1) * 8;
            bf16x8 kh_ = zf, qh_ = zf, ql_ = zf;
            if (quad < 2) {
                kh_ = *(const bf16x8*)&khiS[fo];
                qh_ = *(const bf16x8*)&qhiS[fo];
                ql_ = *(const bf16x8*)&qloS[fo];
            }
            f32x4 sc = {0.f, 0.f, 0.f, 0.f};
            sc = MFMA(kh_, qh_, sc);
            sc = MFMA(kh_, ql_, sc);
            const f32x4 lg = *(const f32x4*)&logitS[c15 * 16 + quad * 4];
            const us4 ew4 = *(const us4*)&ewS[h * 256 + c15 * 16 + quad * 4];
            float s0 = sc[0] * 0.25f + lg[0];
            float s1 = sc[1] * 0.25f + lg[1];
            float s2 = sc[2] * 0.25f + lg[2];
            float s3 = sc[3] * 0.25f + lg[3];
            float mx = fmaxf(fmaxf(s0, s1), fmaxf(s2, s3));
            mx = fmaxf(mx, __shfl_xor(mx, 16));
            mx = fmaxf(mx, __shfl_xor(mx, 32));
            float e0 = __expf(s0 - mx), e1 = __expf(s1 - mx);
            float e2 = __expf(s2 - mx), e3 = __expf(s3 - mx);
            float sm = (e0 + e1) + (e2 + e3);
            sm += __shfl_xor(sm, 16);
            sm += __shfl_xor(sm, 32);
            const float inv = __builtin_amdgcn_rcpf(sm);
            const float p0 = e0 * inv + bf2f(ew4[0]);
            const float p1 = e1 * inv + bf2f(ew4[1]);
            const float p2 = e2 * inv + bf2f(ew4[2]);
            const float p3 = e3 * inv + bf2f(ew4[3]);
            u32x2 pw;
            pw[0] = (unsigned int)f2bf_rn(p0) | ((unsigned int)f2bf_rn(p1) << 16);
            pw[1] = (unsigned int)f2bf_rn(p2) | ((unsigned int)f2bf_rn(p3) << 16);
            *(u32x2*)&pS[wave * 384 + c15 * 24 + quad * 4] = pw;

            bf16x8 pa = zf, vb = zf;
            if (quad < 2) {
                pa = *(const bf16x8*)&pS[wave * 384 + c15 * 24 + (quad & 1) * 8];
                vb = *(const bf16x8*)&vtS[(h * 16 + c15) * 24 + (quad & 1) * 8];
            }
            f32x4 xs = {0.f, 0.f, 0.f, 0.f};
            xs = MFMA(pa, vb, xs);
            #pragma unroll
            for (int r = 0; r < 4; ++r) {
                const int tok = quad * 4 + r;
                float val = xs[r] + greg[r] * vblk;
                mhiS[tok * 136 + h * 16 + c15] = f2bf_rn(val);
            }
        }
        __syncthreads();   // barrier C: x_mid + next-x staged visible

        // ---- output projection ----
        {
            bf16x8 mh[4];
            #pragma unroll
            for (int kk = 0; kk < 4; ++kk)
                mh[kk] = *(const bf16x8*)&mhiS[c15 * 136 + kk * 32 + quad * 8];
            f32x4 acc = {0.f, 0.f, 0.f, 0.f};
            #pragma unroll
            for (int kk = 0; kk < 4; ++kk) acc = MFMA(mh[kk], Wt[kk], acc);
            float* op = out + (size_t)bid * 2048;
            #pragma unroll
            for (int r = 0; r < 4; ++r)
                op[(quad * 4 + r) * 128 + wave * 16 + c15] = acc[r] + bpv;
        }

        mv = mv_n;
        evv = ev_n;
    }
}

extern "C" void kernel_launch(void* const* d_in, const int* in_sizes, int n_in,
                              void* d_out, int out_size, void* d_ws, size_t ws_size,
                              hipStream_t stream) {
    const float* x     = (const float*)d_in[0];
    const int*   amask = (const int*)  d_in[1];
    const float* edge  = (const float*)d_in[2];
    const float* Wqkv  = (const float*)d_in[3];
    const float* bqkv  = (const float*)d_in[4];
    const float* Wproj = (const float*)d_in[5];
    const float* bproj = (const float*)d_in[6];
    const float* eg_w1 = (const float*)d_in[7];
    const float* eg_b1 = (const float*)d_in[8];
    const float* eg_w2 = (const float*)d_in[9];
    const float* eg_b2 = (const float*)d_in[10];
    const float* Wbr   = (const float*)d_in[11];
    const float* bbr   = (const float*)d_in[12];
    float* outp = (float*)d_out;

    unsigned short* Wbig = (unsigned short*)d_ws;                      // 400*128 bf16
    unsigned short* Wp   = (unsigned short*)((char*)d_ws + 400 * 128 * 2);

    hipLaunchKernelGGL(prep_kernel, dim3(264), dim3(256), 0, stream,
                       Wqkv, Wbr, Wproj, Wbig, Wp);
    hipLaunchKernelGGL(leaf_main, dim3(8192 / NITER), dim3(512), 0, stream,
                       x, amask, edge, Wbig, Wp, bqkv, bproj,
                       eg_w1, eg_b1, eg_w2, eg_b2, bbr, outp);
}

// Round 11
// 125.273 us; speedup vs baseline: 1.1072x; 1.1072x over previous
//
#include <hip/hip_runtime.h>
#include <hip/hip_bf16.h>
#include <math.h>

// B=4, NB=2048 -> 8192 leaf blocks of L=16 tokens x C=128; H=8 heads x D=16.
// 512 threads (8 waves), NITER=4 blocks/WG, 2 barriers/iter, single-bf16 path
// (no hi/lo splits: error budget shows x/q rounding is sub-dominant).
typedef __attribute__((ext_vector_type(8))) short bf16x8;
typedef __attribute__((ext_vector_type(4))) float f32x4;
typedef __attribute__((ext_vector_type(4))) unsigned short us4;
typedef __attribute__((ext_vector_type(2))) unsigned int u32x2;

#define NITER 4

static __device__ __forceinline__ unsigned short f2bf_rn(float f) {
    union { __hip_bfloat16 h; unsigned short u; } cv;
    cv.h = __float2bfloat16(f);
    return cv.u;
}
static __device__ __forceinline__ float bf2f(unsigned short u) {
    union { unsigned int i; float f; } cv;
    cv.i = ((unsigned int)u) << 16;
    return cv.f;
}
static __device__ __forceinline__ f32x4 MFMA(bf16x8 a, bf16x8 b, f32x4 c) {
    return __builtin_amdgcn_mfma_f32_16x16x32_bf16(a, b, c, 0, 0, 0);
}
static __device__ __forceinline__ float sigmoid_fast(float t) {
    return __builtin_amdgcn_rcpf(1.f + __expf(-t));
}

// ---- prep: Wbig = bf16([Wqkv(384); Wbr(8); zeros(8)]) [400][128]; Wp = bf16(Wproj)
__global__ __launch_bounds__(256) void prep_kernel(
    const float* __restrict__ Wqkv, const float* __restrict__ Wbr,
    const float* __restrict__ Wproj,
    unsigned short* __restrict__ Wbig, unsigned short* __restrict__ Wp)
{
    int i = blockIdx.x * 256 + threadIdx.x;
    if (i < 400 * 128) {
        int n = i >> 7, k = i & 127;
        float v = (n < 384) ? Wqkv[i] : (n < 392 ? Wbr[(n - 384) * 128 + k] : 0.f);
        Wbig[i] = f2bf_rn(v);
    } else {
        int j = i - 400 * 128;
        if (j < 128 * 128) Wp[j] = f2bf_rn(Wproj[j]);
    }
}

__global__ __launch_bounds__(512) void leaf_main(
    const float* __restrict__ x, const int* __restrict__ mask,
    const float* __restrict__ edge,
    const unsigned short* __restrict__ Wbig, const unsigned short* __restrict__ Wp,
    const float* __restrict__ bqkv, const float* __restrict__ bproj,
    const float* __restrict__ eg_w1, const float* __restrict__ eg_b1,
    const float* __restrict__ eg_w2, const float* __restrict__ eg_b2,
    const float* __restrict__ bbr, float* __restrict__ out)
{
    __shared__ unsigned short qhiS[16 * 136];                  // q rounded bf16
    __shared__ unsigned short khiS[16 * 136];                  // k rounded bf16
    __shared__ unsigned short vtS[128 * 24];                   // [h*16+d][tok(24)]
    __shared__ unsigned short ewS[8 * 256];                    // [h][q*16+k]
    __shared__ float logitS[256];                              // [q*16+k]
    __shared__ unsigned short pS[8 * 16 * 24];                 // per-wave P
    __shared__ unsigned short mhiS[16 * 136];                  // x_mid rounded
    __shared__ unsigned short xhiS[16 * 128];                  // x stage (bf16)
    // total ~34.6 KB

    const int tid  = threadIdx.x;
    const int lane = tid & 63;
    const int wave = tid >> 6;
    const int c15  = lane & 15;
    const int quad = lane >> 4;
    const bf16x8 zf = {0, 0, 0, 0, 0, 0, 0, 0};
    const int bid0 = blockIdx.x * NITER;

    // iteration-invariant
    const unsigned short* wbase = Wbig + c15 * 128 + quad * 8;
    const float bq0 = bqkv[wave * 16 + c15];
    const float bq1 = bqkv[128 + wave * 16 + c15];
    const float bq2 = bqkv[256 + wave * 16 + c15];
    const float bgate = bbr[c15 & 7];
    const float bpv = bproj[wave * 16 + c15];

    // ---- prologue: block 0 inputs ----
    int mv = 0;
    float4 evv = make_float4(0.f, 0.f, 0.f, 0.f);
    if (tid < 256) {
        mv  = mask[(size_t)bid0 * 256 + tid];
        evv = *(const float4*)&edge[((size_t)bid0 * 256 + tid) * 4];
    }
    float4 xv = ((const float4*)(x + (size_t)bid0 * 2048))[tid];

    // W rolling prefetch: slot0 = q-tile(wave), slot1 = k-tile(8+wave)
    bf16x8 Bt[2][4];
    {
        const unsigned short* w0 = wbase + (wave * 16) * 128;
        #pragma unroll
        for (int kk = 0; kk < 4; ++kk) Bt[0][kk] = *(const bf16x8*)(w0 + kk * 32);
        const unsigned short* w1 = wbase + ((8 + wave) * 16) * 128;
        #pragma unroll
        for (int kk = 0; kk < 4; ++kk) Bt[1][kk] = *(const bf16x8*)(w1 + kk * 32);
    }

    // stage x block 0 (rounded bf16, chunk-XOR swizzle)
    {
        int row = tid >> 5, c4 = tid & 31;
        int off = row * 128 + (((c4 >> 1) ^ (row & 7)) << 3) + ((c4 & 1) << 2);
        us4 hi;
        hi[0] = f2bf_rn(xv.x); hi[1] = f2bf_rn(xv.y);
        hi[2] = f2bf_rn(xv.z); hi[3] = f2bf_rn(xv.w);
        *(us4*)&xhiS[off] = hi;
    }
    __syncthreads();   // prologue barrier: x0 staged

    #pragma unroll 1
    for (int it = 0; it < NITER; ++it) {
        const int bid = bid0 + it;
        const bool more = (it + 1 < NITER);

        // next-block loads (retire under this iteration's compute)
        float4 xv_n = make_float4(0.f, 0.f, 0.f, 0.f);
        int mv_n = 0;
        float4 ev_n = make_float4(0.f, 0.f, 0.f, 0.f);
        if (more) {
            xv_n = ((const float4*)(x + (size_t)(bid + 1) * 2048))[tid];
            if (tid < 256) {
                mv_n = mask[(size_t)(bid + 1) * 256 + tid];
                ev_n = *(const float4*)&edge[((size_t)(bid + 1) * 256 + tid) * 4];
            }
        }

        // ---- edge-gate MLP (poly gelu) + mask/logits (waves 0-3) ----
        if (tid < 256) {
            const int q = tid >> 4, k = tid & 15;
            int s = mv;
            s += __shfl_xor(s, 1); s += __shfl_xor(s, 2);
            s += __shfl_xor(s, 4); s += __shfl_xor(s, 8);
            float m = (float)mv;
            if (q == k && s < 1) m = 1.f;
            float bp0, bp1, bp2, bp3;
            if (q == k) { bp0 = bp1 = bp2 = 0.f; bp3 = 1.f; }
            else        { bp0 = evv.x; bp1 = evv.y; bp2 = evv.z; bp3 = evv.w; }
            logitS[tid] = (m == 0.f) ? -INFINITY : bp3;
            float ew[8];
            #pragma unroll
            for (int h = 0; h < 8; ++h) ew[h] = eg_b2[h];
            #pragma unroll
            for (int j = 0; j < 16; ++j) {
                float z = eg_w1[j * 4 + 0] * bp0 + eg_w1[j * 4 + 1] * bp1 +
                          eg_w1[j * 4 + 2] * bp2 + eg_w1[j * 4 + 3] * bp3 + eg_b1[j];
                float u = z * z;
                float w = __builtin_fmaf(-0.0664904f, u, 0.3989423f);
                float g = z * __builtin_fmaf(z, w, 0.5f);
                #pragma unroll
                for (int h = 0; h < 8; ++h) ew[h] = __builtin_fmaf(eg_w2[h * 16 + j], g, ew[h]);
            }
            #pragma unroll
            for (int h = 0; h < 8; ++h)
                ewS[h * 256 + tid] = (m == 0.f) ? (unsigned short)0
                                   : (unsigned short)(__float_as_uint(ew[h]) >> 16);
        }

        // ---- A-fragments from LDS ----
        bf16x8 ah[4];
        #pragma unroll
        for (int kk = 0; kk < 4; ++kk) {
            int off = c15 * 128 + (((kk * 4 + quad) ^ (c15 & 7)) << 3);
            ah[kk] = *(const bf16x8*)&xhiS[off];
        }

        const int colq = wave * 16 + c15;
        float vblk;
        float greg[4];

        // ---- tile q ----
        {
            f32x4 acc = {0.f, 0.f, 0.f, 0.f};
            #pragma unroll
            for (int kk = 0; kk < 4; ++kk) acc = MFMA(ah[kk], Bt[0][kk], acc);
            const unsigned short* w2 = wbase + ((16 + wave) * 16) * 128;  // v-tile
            #pragma unroll
            for (int kk = 0; kk < 4; ++kk) Bt[0][kk] = *(const bf16x8*)(w2 + kk * 32);
            #pragma unroll
            for (int r = 0; r < 4; ++r)
                qhiS[(quad * 4 + r) * 136 + colq] = f2bf_rn(acc[r] + bq0);
        }

        // ---- tile k ----
        {
            f32x4 acc = {0.f, 0.f, 0.f, 0.f};
            #pragma unroll
            for (int kk = 0; kk < 4; ++kk) acc = MFMA(ah[kk], Bt[1][kk], acc);
            const unsigned short* w3 = wbase + 384 * 128;                 // gate tile
            #pragma unroll
            for (int kk = 0; kk < 4; ++kk) Bt[1][kk] = *(const bf16x8*)(w3 + kk * 32);
            #pragma unroll
            for (int r = 0; r < 4; ++r)
                khiS[(quad * 4 + r) * 136 + colq] = f2bf_rn(acc[r] + bq1);
        }

        // ---- tile v (transposed; v_blk in-register) ----
        {
            f32x4 acc = {0.f, 0.f, 0.f, 0.f};
            #pragma unroll
            for (int kk = 0; kk < 4; ++kk) acc = MFMA(ah[kk], Bt[0][kk], acc);
            const unsigned short* w0 = wbase + (wave * 16) * 128;         // next q
            #pragma unroll
            for (int kk = 0; kk < 4; ++kk) Bt[0][kk] = *(const bf16x8*)(w0 + kk * 32);
            us4 vw;
            #pragma unroll
            for (int r = 0; r < 4; ++r) vw[r] = f2bf_rn(acc[r] + bq2);
            *(us4*)&vtS[colq * 24 + quad * 4] = vw;
            float s = acc[0] + acc[1] + acc[2] + acc[3];
            s += __shfl_xor(s, 16);
            s += __shfl_xor(s, 32);
            vblk = s * 0.0625f + bq2;     // per-lane = v_blk[wave*16+c15]
        }

        // ---- tile gate (every wave; keep own column via shuffle) ----
        {
            f32x4 acc = {0.f, 0.f, 0.f, 0.f};
            #pragma unroll
            for (int kk = 0; kk < 4; ++kk) acc = MFMA(ah[kk], Bt[1][kk], acc);
            const unsigned short* w1 = wbase + ((8 + wave) * 16) * 128;   // next k
            #pragma unroll
            for (int kk = 0; kk < 4; ++kk) Bt[1][kk] = *(const bf16x8*)(w1 + kk * 32);
            const int src = (lane & 48) | wave;
            #pragma unroll
            for (int r = 0; r < 4; ++r) {
                float sg = sigmoid_fast(acc[r] + bgate);
                greg[r] = __shfl(sg, src);        // g[tok=quad*4+r][h=wave]
            }
        }
        __syncthreads();   // barrier B: qkv/MLP visible; x-stage reads done

        // stage NEXT block's x (overlaps attention; visibility via barrier C)
        if (more) {
            int row = tid >> 5, c4 = tid & 31;
            int off = row * 128 + (((c4 >> 1) ^ (row & 7)) << 3) + ((c4 & 1) << 2);
            us4 hi;
            hi[0] = f2bf_rn(xv_n.x); hi[1] = f2bf_rn(xv_n.y);
            hi[2] = f2bf_rn(xv_n.z); hi[3] = f2bf_rn(xv_n.w);
            *(us4*)&xhiS[off] = hi;
        }

        // proj weights prefetch (retire under attention)
        bf16x8 Wt[4];
        {
            const unsigned short* wp = Wp + (wave * 16 + c15) * 128 + quad * 8;
            #pragma unroll
            for (int kk = 0; kk < 4; ++kk) Wt[kk] = *(const bf16x8*)(wp + kk * 32);
        }

        // ---- attention, swapped QK^T (head h = wave) ----
        {
            const int h = wave;
            const int fo = c15 * 136 + h * 16 + (quad & 1) * 8;
            bf16x8 kh_ = zf, qh_ = zf;
            if (quad < 2) {
                kh_ = *(const bf16x8*)&khiS[fo];
                qh_ = *(const bf16x8*)&qhiS[fo];
            }
            f32x4 sc = {0.f, 0.f, 0.f, 0.f};
            sc = MFMA(kh_, qh_, sc);
            const f32x4 lg = *(const f32x4*)&logitS[c15 * 16 + quad * 4];
            const us4 ew4 = *(const us4*)&ewS[h * 256 + c15 * 16 + quad * 4];
            float s0 = sc[0] * 0.25f + lg[0];
            float s1 = sc[1] * 0.25f + lg[1];
            float s2 = sc[2] * 0.25f + lg[2];
            float s3 = sc[3] * 0.25f + lg[3];
            float mx = fmaxf(fmaxf(s0, s1), fmaxf(s2, s3));
            mx = fmaxf(mx, __shfl_xor(mx, 16));
            mx = fmaxf(mx, __shfl_xor(mx, 32));
            float e0 = __expf(s0 - mx), e1 = __expf(s1 - mx);
            float e2 = __expf(s2 - mx), e3 = __expf(s3 - mx);
            float sm = (e0 + e1) + (e2 + e3);
            sm += __shfl_xor(sm, 16);
            sm += __shfl_xor(sm, 32);
            const float inv = __builtin_amdgcn_rcpf(sm);
            const float p0 = e0 * inv + bf2f(ew4[0]);
            const float p1 = e1 * inv + bf2f(ew4[1]);
            const float p2 = e2 * inv + bf2f(ew4[2]);
            const float p3 = e3 * inv + bf2f(ew4[3]);
            u32x2 pw;
            pw[0] = (unsigned int)f2bf_rn(p0) | ((unsigned int)f2bf_rn(p1) << 16);
            pw[1] = (unsigned int)f2bf_rn(p2) | ((unsigned int)f2bf_rn(p3) << 16);
            *(u32x2*)&pS[wave * 384 + c15 * 24 + quad * 4] = pw;

            bf16x8 pa = zf, vb = zf;
            if (quad < 2) {
                pa = *(const bf16x8*)&pS[wave * 384 + c15 * 24 + (quad & 1) * 8];
                vb = *(const bf16x8*)&vtS[(h * 16 + c15) * 24 + (quad & 1) * 8];
            }
            f32x4 xs = {0.f, 0.f, 0.f, 0.f};
            xs = MFMA(pa, vb, xs);
            #pragma unroll
            for (int r = 0; r < 4; ++r) {
                const int tok = quad * 4 + r;
                float val = xs[r] + greg[r] * vblk;
                mhiS[tok * 136 + h * 16 + c15] = f2bf_rn(val);
            }
        }
        __syncthreads();   // barrier C: x_mid + next-x staged visible

        // ---- output projection ----
        {
            bf16x8 mh[4];
            #pragma unroll
            for (int kk = 0; kk < 4; ++kk)
                mh[kk] = *(const bf16x8*)&mhiS[c15 * 136 + kk * 32 + quad * 8];
            f32x4 acc = {0.f, 0.f, 0.f, 0.f};
            #pragma unroll
            for (int kk = 0; kk < 4; ++kk) acc = MFMA(mh[kk], Wt[kk], acc);
            float* op = out + (size_t)bid * 2048;
            #pragma unroll
            for (int r = 0; r < 4; ++r)
                op[(quad * 4 + r) * 128 + wave * 16 + c15] = acc[r] + bpv;
        }

        mv = mv_n;
        evv = ev_n;
    }
}

extern "C" void kernel_launch(void* const* d_in, const int* in_sizes, int n_in,
                              void* d_out, int out_size, void* d_ws, size_t ws_size,
                              hipStream_t stream) {
    const float* x     = (const float*)d_in[0];
    const int*   amask = (const int*)  d_in[1];
    const float* edge  = (const float*)d_in[2];
    const float* Wqkv  = (const float*)d_in[3];
    const float* bqkv  = (const float*)d_in[4];
    const float* Wproj = (const float*)d_in[5];
    const float* bproj = (const float*)d_in[6];
    const float* eg_w1 = (const float*)d_in[7];
    const float* eg_b1 = (const float*)d_in[8];
    const float* eg_w2 = (const float*)d_in[9];
    const float* eg_b2 = (const float*)d_in[10];
    const float* Wbr   = (const float*)d_in[11];
    const float* bbr   = (const float*)d_in[12];
    float* outp = (float*)d_out;

    unsigned short* Wbig = (unsigned short*)d_ws;                      // 400*128 bf16
    unsigned short* Wp   = (unsigned short*)((char*)d_ws + 400 * 128 * 2);

    hipLaunchKernelGGL(prep_kernel, dim3(264), dim3(256), 0, stream,
                       Wqkv, Wbr, Wproj, Wbig, Wp);
    hipLaunchKernelGGL(leaf_main, dim3(8192 / NITER), dim3(512), 0, stream,
                       x, amask, edge, Wbig, Wp, bqkv, bproj,
                       eg_w1, eg_b1, eg_w2, eg_b2, bbr, outp);
}